// Round 19
// baseline (325.383 us; speedup 1.0000x reference)
//
#include <hip/hip_runtime.h>
#include <stdint.h>

using u16 = unsigned short;
using u32 = unsigned int;
using bf16x8 = __bf16 __attribute__((ext_vector_type(8)));
using f32x4  = float __attribute__((ext_vector_type(4)));

__device__ __forceinline__ float bflo(u32 u){ return __uint_as_float(u << 16); }
__device__ __forceinline__ float bfhi(u32 u){ return __uint_as_float(u & 0xffff0000u); }
__device__ __forceinline__ u16 f2bf(float f){
  u32 u = __float_as_uint(f);
  u += 0x7fffu + ((u >> 16) & 1u);
  return (u16)(u >> 16);
}
// manual RTNE pack (0.046875-pedigree arithmetic)
__device__ __forceinline__ u32 pk2(float a, float b){
  return (u32)f2bf(a) | ((u32)f2bf(b) << 16);
}
__device__ __forceinline__ void gload16(const void* g, void* l){
  __builtin_amdgcn_global_load_lds(
      (const __attribute__((address_space(1))) void*)(uintptr_t)(g),
      (__attribute__((address_space(3))) void*)(uintptr_t)(l), 16, 0, 0);
}

// ---------------- prep: WpT = (diag(lnw)Win)^T, WoutT, g1 = lnw^T Win, g2 = lnb^T Win ----
__global__ __launch_bounds__(256) void prep_k(const float* __restrict__ Win,
                                              const float* __restrict__ Wout,
                                              const float* __restrict__ lnw,
                                              const float* __restrict__ lnb,
                                              u16* __restrict__ WpT,
                                              u16* __restrict__ WoutT,
                                              float* __restrict__ g1,
                                              float* __restrict__ g2){
  __shared__ float tile[32][33];
  __shared__ float red[2][8][32];
  int bid = blockIdx.x;
  if (bid < 512){
    int bz = bid >> 8, bi = bid & 255;
    int bx = bi & 15, by = bi >> 4;
    const float* src = bz ? Wout : Win;
    u16* dst = bz ? WoutT : WpT;
    int tx = threadIdx.x & 31, ty = threadIdx.x >> 5;
    int c0 = bx * 32, r0 = by * 32;
#pragma unroll
    for (int i = 0; i < 4; ++i)
      tile[ty + i*8][tx] = src[(size_t)(r0 + ty + i*8)*512 + c0 + tx];
    __syncthreads();
    float sc = bz ? 1.f : lnw[r0 + tx];
#pragma unroll
    for (int i = 0; i < 4; ++i)
      dst[(size_t)(c0 + ty + i*8)*512 + r0 + tx] = f2bf(tile[tx][ty + i*8] * sc);
  } else {
    int bi = bid - 512;                       // 0..15
    int col = bi*32 + (threadIdx.x & 31);
    int s = threadIdx.x >> 5;                 // 0..7
    float p1 = 0.f, p2 = 0.f;
    for (int kk = 0; kk < 64; ++kk){
      int k = s*64 + kk;
      float wv = Win[(size_t)k*512 + col];
      p1 += lnw[k]*wv; p2 += lnb[k]*wv;
    }
    red[0][s][threadIdx.x & 31] = p1;
    red[1][s][threadIdx.x & 31] = p2;
    __syncthreads();
    if (threadIdx.x < 32){
      float a1 = 0.f, a2 = 0.f;
#pragma unroll
      for (int s2 = 0; s2 < 8; ++s2){ a1 += red[0][s2][threadIdx.x]; a2 += red[1][s2][threadIdx.x]; }
      g1[bi*32 + threadIdx.x] = a1;
      g2[bi*32 + threadIdx.x] = a2;
    }
  }
}

// ---------------- fused LN-GEMM projection body, 128x128 tile, BK=64 ----------------
// 2-deep x reg-prefetch + double-buffered W, kt loop FULLY UNROLLED so all xr slot
// indices are compile-time (round-15's scratch bug was runtime xr[kt&1] indexing).
// barrier1(kt) = vmcnt(8) lgkmcnt(0): drains W(kt) (older), keeps x(kt+1)'s 8 loads
// in flight.  barrier2 = lgkmcnt(0)-only raw barrier.
// GEMM on raw bf16(x); LN applied in epilogue: f = rs*(x@Wp - mu*g1) + g2.
template<int ORIENT, int FSTAT>
__device__ __forceinline__ void proj_body(
    const float* __restrict__ X, const u16* __restrict__ Wp,
    const float* __restrict__ g1, const float* __restrict__ g2,
    u16* __restrict__ C, float* __restrict__ fstat, int ldC, int bid,
    char* sW, char* sX, float* sF){
  float* sMu = sF;        float* sRs = sF + 128;
  float* sG1 = sF + 256;  float* sG2 = sF + 384;
  const int t = threadIdx.x, w = t >> 6, l = t & 63;
  const int wr = w >> 1, wc = w & 1;
  const int lr = l & 15, lg = l >> 4;
  int bx, by;
  if (ORIENT == 0){ bx = bid & 127; by = bid >> 7; }          // +128 siblings share XCD
  else { int j = bid >> 3; bx = j & 3; by = (bid & 7) + 8*(j >> 2); }
  const int row0 = bx * 128, col0 = by * 128;
  const int xbase = (ORIENT == 0) ? row0 : col0;   // token rows of X
  const int wbase = (ORIENT == 0) ? col0 : row0;   // inner rows of Wp

  const int sc = t >> 3, k8 = t & 7;
  const int sso = (k8*16) ^ ((sc & 7) << 4);
  const char* Wpp = (const char*)Wp + ((size_t)(wbase + sc) << 10) + sso;
  const float* Xp = X + ((size_t)(xbase + sc) << 9) + k8*8;

  if (t < 128){ sG1[t] = g1[wbase + t]; sG2[t] = g2[wbase + t]; }

  float xr[2][4][8];
  float psum[4] = {}, pss[4] = {};
  f32x4 acc[4][4] = {};

  auto XLOAD = [&](int kt, int slot){
#pragma unroll
    for (int ii = 0; ii < 4; ++ii){
      const float* p = Xp + ii*(32*512) + kt*64;
      float4 a = *(const float4*)p, c4 = *(const float4*)(p + 4);
      xr[slot][ii][0]=a.x;  xr[slot][ii][1]=a.y;  xr[slot][ii][2]=a.z;  xr[slot][ii][3]=a.w;
      xr[slot][ii][4]=c4.x; xr[slot][ii][5]=c4.y; xr[slot][ii][6]=c4.z; xr[slot][ii][7]=c4.w;
    }
  };
  auto XWRITE = [&](int slot){
#pragma unroll
    for (int ii = 0; ii < 4; ++ii){
#pragma unroll
      for (int e = 0; e < 8; ++e){ psum[ii] += xr[slot][ii][e]; pss[ii] += xr[slot][ii][e]*xr[slot][ii][e]; }
      uint4 pk;
      pk.x = pk2(xr[slot][ii][0], xr[slot][ii][1]); pk.y = pk2(xr[slot][ii][2], xr[slot][ii][3]);
      pk.z = pk2(xr[slot][ii][4], xr[slot][ii][5]); pk.w = pk2(xr[slot][ii][6], xr[slot][ii][7]);
      *(uint4*)(sX + (sc + ii*32)*128 + sso) = pk;
    }
  };
  auto WSTAGE = [&](int kt, int buf){
#pragma unroll
    for (int ii = 0; ii < 4; ++ii)
      gload16(Wpp + (size_t)ii*32768 + kt*128, sW + buf*16384 + ii*4096 + w*1024);
  };

  XLOAD(0, 0);          // x(0)  (oldest)
  WSTAGE(0, 0);         // W(0) -> buf 0
  XLOAD(1, 1);          // x(1)
#pragma unroll
  for (int kt = 0; kt < 8; ++kt){
    // Phase A: pack x(kt) into LDS (compiler waits x(kt)'s loads via reg deps)
    XWRITE(kt & 1);
    // barrier1: W(kt) landed in LDS; x(kt+1) prefetch stays in flight
    if (kt < 7) asm volatile("s_waitcnt vmcnt(8) lgkmcnt(0)" ::: "memory");
    else        asm volatile("s_waitcnt vmcnt(0) lgkmcnt(0)" ::: "memory");
    __builtin_amdgcn_s_barrier();
    __builtin_amdgcn_sched_barrier(0);
    // Phase B: issue next W (other buffer), then deep x prefetch, then compute
    if (kt < 7) WSTAGE(kt + 1, (kt + 1) & 1);
    if (kt < 6) XLOAD(kt + 2, kt & 1);
    __builtin_amdgcn_sched_barrier(0);
    const char* wB = sW + (kt & 1)*16384;
    const char* aB = (ORIENT == 0) ? sX : wB;
    const char* bB = (ORIENT == 0) ? wB : sX;
#pragma unroll
    for (int kk = 0; kk < 2; ++kk){
      bf16x8 af[4], bfg[4];
#pragma unroll
      for (int m = 0; m < 4; ++m){
        int r = wr*64 + m*16 + lr;
        af[m] = *(const bf16x8*)(aB + r*128 + ((kk*64 + lg*16) ^ ((r & 7) << 4)));
      }
#pragma unroll
      for (int n = 0; n < 4; ++n){
        int r = wc*64 + n*16 + lr;
        bfg[n] = *(const bf16x8*)(bB + r*128 + ((kk*64 + lg*16) ^ ((r & 7) << 4)));
      }
#pragma unroll
      for (int m = 0; m < 4; ++m)
#pragma unroll
        for (int n = 0; n < 4; ++n)
          acc[m][n] = __builtin_amdgcn_mfma_f32_16x16x32_bf16(af[m], bfg[n], acc[m][n], 0, 0, 0);
    }
    // barrier2: lgkm-only raw barrier — global prefetches stay in flight;
    // seals all waves' ds_reads of buf kt&1 and sX before overwrite.
    asm volatile("s_waitcnt lgkmcnt(0)" ::: "memory");
    __builtin_amdgcn_s_barrier();
    __builtin_amdgcn_sched_barrier(0);
  }

  // LN row stats: reduce over the 8 k8-lanes sharing each staged row
#pragma unroll
  for (int ii = 0; ii < 4; ++ii){
    float s = psum[ii], s2 = pss[ii];
#pragma unroll
    for (int off = 1; off < 8; off <<= 1){ s += __shfl_xor(s, off); s2 += __shfl_xor(s2, off); }
    if (k8 == 0){
      float mu = s * (1.f/512.f);
      sMu[sc + ii*32] = mu;
      sRs[sc + ii*32] = rsqrtf(s2 * (1.f/512.f) - mu*mu + 1e-5f);
    }
  }
  __syncthreads();

  // epilogue: f = rs*(acc - mu*g1) + g2, write bf16, emit f-stats
  float cs[4] = {}, cs2[4] = {};
#pragma unroll
  for (int m = 0; m < 4; ++m){
#pragma unroll
    for (int q = 0; q < 4; ++q){
      int ri = wr*64 + m*16 + lg*4 + q;
      float rsv = 0.f, muv = 0.f, g1r = 0.f, g2r = 0.f;
      if (ORIENT == 0){ rsv = sRs[ri]; muv = sMu[ri]; }
      else { g1r = sG1[ri]; g2r = sG2[ri]; }
      float fv[4];
#pragma unroll
      for (int n = 0; n < 4; ++n){
        int ci = wc*64 + n*16 + lr;
        float a = acc[m][n][q];
        if (ORIENT == 0) fv[n] = rsv*(a - muv*sG1[ci]) + sG2[ci];
        else             fv[n] = sRs[ci]*(a - sMu[ci]*g1r) + g2r;
        C[(size_t)(row0 + ri)*ldC + (col0 + ci)] = f2bf(fv[n]);
        if (FSTAT == 2){ cs[n] += fv[n]; cs2[n] += fv[n]*fv[n]; }
      }
      if (FSTAT == 1){
        float s  = (fv[0]+fv[1]) + (fv[2]+fv[3]);
        float s2 = (fv[0]*fv[0]+fv[1]*fv[1]) + (fv[2]*fv[2]+fv[3]*fv[3]);
#pragma unroll
        for (int off = 1; off < 16; off <<= 1){ s += __shfl_xor(s, off); s2 += __shfl_xor(s2, off); }
        if (lr == 0){
          int head = (col0 >> 6) + wc;
          *(float2*)(fstat + ((size_t)(row0 + ri)*8 + head)*2) = make_float2(s, s2);
        }
      }
    }
  }
  if (FSTAT == 2){
    int head = (row0 >> 6) + wr;
#pragma unroll
    for (int n = 0; n < 4; ++n){
      float s = cs[n], s2 = cs2[n];
      s += __shfl_xor(s, 16); s2 += __shfl_xor(s2, 16);
      s += __shfl_xor(s, 32); s2 += __shfl_xor(s2, 32);
      if (lg == 0){
        int tok = col0 + wc*64 + n*16 + lr;
        *(float2*)(fstat + ((size_t)tok*8 + head)*2) = make_float2(s, s2);
      }
    }
  }
}

// ---------------- merged Q/K/V projection launch: 1536 blocks ----------------
__global__ __launch_bounds__(256, 3) void proj_k(
    const float* __restrict__ q, const float* __restrict__ k, const float* __restrict__ v,
    const u16* __restrict__ Wp, const float* __restrict__ g1, const float* __restrict__ g2,
    u16* __restrict__ fq, u16* __restrict__ kT, u16* __restrict__ vT,
    float* __restrict__ qstat, float* __restrict__ kstat){
  __shared__ __align__(16) char sW[32768];     // double-buffered W
  __shared__ __align__(16) char sX[16384];
  __shared__ float sF[512];
  int bid = blockIdx.x;
  if (bid < 512)
    proj_body<0,1>(q, Wp, g1, g2, fq, qstat, 512, bid, sW, sX, sF);
  else if (bid < 1024)
    proj_body<1,2>(k, Wp, g1, g2, kT, kstat, 16384, bid - 512, sW, sX, sF);
  else
    proj_body<1,0>(v, Wp, g1, g2, vT, nullptr, 16384, bid - 1024, sW, sX, sF);
}

// ---------------- out GEMM (deep-pipelined): C = ao @ WoutT^T + bias ----------------
__global__ __launch_bounds__(256) void outgemm_k(
    const u16* __restrict__ A, const u16* __restrict__ B,
    float* __restrict__ Cf, const float* __restrict__ bias){
  __shared__ __align__(16) char sM[65536];
  const int t = threadIdx.x, w = t >> 6, l = t & 63;
  const int wr = w >> 1, wc = w & 1;
  const int lr = l & 15, lg = l >> 4;
  const int bx = blockIdx.x & 127, by = blockIdx.x >> 7;
  const int row0 = bx*128, col0 = by*128;

  const int spr = t >> 3, se = (t & 7) ^ (spr & 7);
  const int srow = spr*2 + (se >> 2), sk16 = se & 3;
  const char* Ap0 = (const char*)A + ((size_t)(row0 + srow) << 10) + sk16*16;
  const char* Bp0 = (const char*)B + ((size_t)(col0 + srow) << 10) + sk16*16;
  const int ldst = w*1024 + l*16;

  const int qf = ((((lr & 1) << 2) | lg) ^ ((lr >> 1) & 7)) * 16;
  const int afb = wr*4096 + (lr >> 1)*128 + qf;
  const int bfb = wc*4096 + (lr >> 1)*128 + qf;

  f32x4 acc[4][4] = {};

  auto STAGE = [&](int kt, int buf){
    char* d = sM + buf*16384;
    gload16(Ap0 + kt*64,         d + ldst);
    gload16(Ap0 + 65536 + kt*64, d + 4096 + ldst);
    gload16(Bp0 + kt*64,         d + 8192 + ldst);
    gload16(Bp0 + 65536 + kt*64, d + 12288 + ldst);
  };

  STAGE(0, 0); STAGE(1, 1); STAGE(2, 2);
#pragma unroll
  for (int kt = 0; kt < 16; ++kt){
    if (kt < 14)       asm volatile("s_waitcnt vmcnt(8)" ::: "memory");
    else if (kt == 14) asm volatile("s_waitcnt vmcnt(4)" ::: "memory");
    else               asm volatile("s_waitcnt vmcnt(0)" ::: "memory");
    __builtin_amdgcn_s_barrier();
    __builtin_amdgcn_sched_barrier(0);
    if (kt < 13) STAGE(kt + 3, (kt + 3) & 3);
    const char* aR = sM + (kt & 3)*16384;
    const char* bR = aR + 8192;
    bf16x8 af[4], bfg[4];
#pragma unroll
    for (int m = 0; m < 4; ++m) af[m]  = *(const bf16x8*)(aR + afb + m*1024);
#pragma unroll
    for (int n = 0; n < 4; ++n) bfg[n] = *(const bf16x8*)(bR + bfb + n*1024);
#pragma unroll
    for (int m = 0; m < 4; ++m)
#pragma unroll
      for (int n = 0; n < 4; ++n)
        acc[m][n] = __builtin_amdgcn_mfma_f32_16x16x32_bf16(af[m], bfg[n], acc[m][n], 0, 0, 0);
  }

#pragma unroll
  for (int m = 0; m < 4; ++m){
#pragma unroll
    for (int qq = 0; qq < 4; ++qq){
      int r = row0 + wr*64 + m*16 + lg*4 + qq;
#pragma unroll
      for (int n = 0; n < 4; ++n){
        int cc = col0 + wc*64 + n*16 + lr;
        Cf[(size_t)r*512 + cc] = acc[m][n][qq] + bias[cc];
      }
    }
  }
}

// ---------------- attention: per (h,b), factored rank-64 form, MFMA ----------------
__global__ __launch_bounds__(512) void attn_k(
    const u16* __restrict__ fq, const u16* __restrict__ kT, const u16* __restrict__ vT,
    const float* __restrict__ qstat, const float* __restrict__ kstat,
    u16* __restrict__ ao,
    const float* __restrict__ cwr, const float* __restrict__ vwr){
  __shared__ __align__(16) char smem[131072 + 1664*4];
  float* sStat = (float*)(smem + 131072);
  float* sS1 = sStat + 1536;
  float* sS2 = sStat + 1600;

  const int t = threadIdx.x, w = t >> 6, l = t & 63;
  const int lr = l & 15, lg = l >> 4;
  const int h = blockIdx.x & 7, b = blockIdx.x >> 3;

  float cwv = 1.f/(1.f + __expf(-*cwr));
  float vwv = 1.f/(1.f + __expf(-*vwr));
  float cosw = 1.f - cwv - vwv;

  const char* kTb = (const char*)kT + (size_t)h*64*32768 + (size_t)b*1024;
  const char* vTb = (const char*)vT + (size_t)h*64*32768 + (size_t)b*1024;
#pragma unroll
  for (int ii = 0; ii < 8; ++ii){
    int c = ii*512 + t, d = c >> 6, u = c & 63;
    int so = d*32768 + ((u ^ (d & 7)) << 4);
    gload16(kTb + so, smem + ii*8192 + w*1024);
    gload16(vTb + so, smem + 65536 + ii*8192 + w*1024);
  }
  {
    float2 ksr = *(const float2*)(kstat + ((size_t)(b*512 + t)*8 + h)*2);
    float mk = ksr.x * (1.f/64.f);
    sStat[t]        = rsqrtf(ksr.y);
    sStat[512 + t]  = mk;
    sStat[1024 + t] = (ksr.y - 64.f*mk*mk) * (1.f/63.f);
  }
  __syncthreads();

  const int jt = (w >> 1), itp = (w & 1);
  f32x4 m2acc[2] = {}, m1acc[2] = {};
  {
    const int j = jt*16 + lr;
#pragma unroll
    for (int ks = 0; ks < 16; ++ks){
      int u = ks*4 + lg;
      bf16x8 af = *(const bf16x8*)(smem + 65536 + j*1024 + ((u ^ (j & 7)) << 4));
#pragma unroll
      for (int tt = 0; tt < 2; ++tt){
        int i = (itp*2 + tt)*16 + lr;
        bf16x8 bf = *(const bf16x8*)(smem + i*1024 + ((u ^ (i & 7)) << 4));
        m2acc[tt] = __builtin_amdgcn_mfma_f32_16x16x32_bf16(af, bf, m2acc[tt], 0, 0, 0);
      }
    }
  }
  {
    int j = t >> 3, g = t & 7;
    float p1 = 0.f, p2 = 0.f;
#pragma unroll
    for (int uu = 0; uu < 8; ++uu){
      int ut = g*8 + uu;
      uint4 uv = *(const uint4*)(smem + 65536 + j*1024 + ((ut ^ (j & 7)) << 4));
      int m0 = ut*8;
      float4 mk0 = *(const float4*)(sStat + 512 + m0);
      float4 mk1 = *(const float4*)(sStat + 512 + m0 + 4);
      float4 kv0 = *(const float4*)(sStat + 1024 + m0);
      float4 kv1 = *(const float4*)(sStat + 1024 + m0 + 4);
      float v0=bflo(uv.x),v1=bfhi(uv.x),v2=bflo(uv.y),v3=bfhi(uv.y);
      float v4=bflo(uv.z),v5=bfhi(uv.z),v6=bflo(uv.w),v7=bfhi(uv.w);
      p1 += v0*mk0.x + v1*mk0.y + v2*mk0.z + v3*mk0.w
          + v4*mk1.x + v5*mk1.y + v6*mk1.z + v7*mk1.w;
      p2 += v0*kv0.x + v1*kv0.y + v2*kv0.z + v3*kv0.w
          + v4*kv1.x + v5*kv1.y + v6*kv1.z + v7*kv1.w;
    }
#pragma unroll
    for (int off = 1; off < 8; off <<= 1){ p1 += __shfl_xor(p1, off); p2 += __shfl_xor(p2, off); }
    if (g == 0){ sS1[j] = p1; sS2[j] = p2; }
  }
  __syncthreads();

#pragma unroll
  for (int ii = 0; ii < 32; ++ii){
    int wd = ii*512 + t;
    int d = wd >> 8, o = wd & 255, ud = o >> 2, p = o & 3;
    int m0 = ((ud ^ (d & 7)) << 3) + p*2;
    u32 uv = *(u32*)(smem + wd*4);
    *(u32*)(smem + wd*4) = pk2(bflo(uv)*sStat[m0], bfhi(uv)*sStat[m0+1]);
  }
  __syncthreads();

  {
    const int j = jt*16 + lr;
#pragma unroll
    for (int ks = 0; ks < 16; ++ks){
      int u = ks*4 + lg;
      bf16x8 af = *(const bf16x8*)(smem + 65536 + j*1024 + ((u ^ (j & 7)) << 4));
#pragma unroll
      for (int tt = 0; tt < 2; ++tt){
        int i = (itp*2 + tt)*16 + lr;
        bf16x8 bf = *(const bf16x8*)(smem + i*1024 + ((u ^ (i & 7)) << 4));
        m1acc[tt] = __builtin_amdgcn_mfma_f32_16x16x32_bf16(af, bf, m1acc[tt], 0, 0, 0);
      }
    }
  }
  __syncthreads();

#pragma unroll
  for (int tt = 0; tt < 2; ++tt){
#pragma unroll
    for (int q = 0; q < 4; ++q){
      int j = jt*16 + lg*4 + q;
      int i = (itp*2 + tt)*16 + lr;
      int bo = j*128 + (((i >> 3) ^ (j & 7)) << 4) + (i & 7)*2;
      *(u16*)(smem + bo)        = f2bf(m1acc[tt][q]);
      *(u16*)(smem + 8192 + bo) = f2bf(m2acc[tt][q]);
    }
  }
  const char* fqb = (const char*)fq + (size_t)b*524288 + h*128;
#pragma unroll
  for (int ii = 0; ii < 8; ++ii){
    int c = ii*512 + t, n = c >> 3, u = c & 7;
    gload16(fqb + n*1024 + ((u ^ (n & 7)) << 4), smem + 65536 + ii*8192 + w*1024);
  }
  __syncthreads();

  float s1v[4], s2v[4];
#pragma unroll
  for (int nt = 0; nt < 4; ++nt){ s1v[nt] = sS1[nt*16 + lr]; s2v[nt] = sS2[nt*16 + lr]; }
  const float Bc = cwv * (1.f/64.f);

#pragma unroll
  for (int mt = 0; mt < 4; ++mt){
    f32x4 a1[4] = {}, a2[4] = {};
    const int n = w*64 + mt*16 + lr;
#pragma unroll
    for (int kk = 0; kk < 2; ++kk){
      int u = kk*4 + lg;
      bf16x8 af = *(const bf16x8*)(smem + 65536 + n*128 + ((u ^ (n & 7)) << 4));
#pragma unroll
      for (int nt = 0; nt < 4; ++nt){
        int j = nt*16 + lr;
        bf16x8 b1 = *(const bf16x8*)(smem + j*128 + ((u ^ (j & 7)) << 4));
        bf16x8 b2 = *(const bf16x8*)(smem + 8192 + j*128 + ((u ^ (j & 7)) << 4));
        a1[nt] = __builtin_amdgcn_mfma_f32_16x16x32_bf16(af, b1, a1[nt], 0, 0, 0);
        a2[nt] = __builtin_amdgcn_mfma_f32_16x16x32_bf16(af, b2, a2[nt], 0, 0, 0);
      }
    }
#pragma unroll
    for (int q = 0; q < 4; ++q){
      int nr = w*64 + mt*16 + lg*4 + q;
      float2 qs = *(const float2*)(qstat + ((size_t)(b*512 + nr)*8 + h)*2);
      float mq = qs.x * (1.f/64.f);
      float An = cosw * rsqrtf(qs.y);
      float Cn = -cwv * mq;
      float En = vwv * (1.f/64.f) * ((qs.y - 64.f*mq*mq) * (1.f/63.f));
      char* op = (char*)ao + ((size_t)(b*512 + nr)*512 + h*64)*2;
#pragma unroll
      for (int nt = 0; nt < 4; ++nt){
        float ov = An*a1[nt][q] + Bc*a2[nt][q] + Cn*s1v[nt] + En*s2v[nt];
        *(u16*)(op + (nt*16 + lr)*2) = f2bf(ov);
      }
    }
  }
}

// ---------------- launch ----------------
extern "C" void kernel_launch(void* const* d_in, const int* in_sizes, int n_in,
                              void* d_out, int out_size, void* d_ws, size_t ws_size,
                              hipStream_t stream){
  const float* q    = (const float*)d_in[0];
  const float* k    = (const float*)d_in[1];
  const float* v    = (const float*)d_in[2];
  const float* lnw  = (const float*)d_in[3];
  const float* lnb  = (const float*)d_in[4];
  const float* Win  = (const float*)d_in[5];
  const float* Wout = (const float*)d_in[6];
  const float* bout = (const float*)d_in[7];
  const float* cwr  = (const float*)d_in[8];
  const float* vwr  = (const float*)d_in[9];

  char* ws = (char*)d_ws;
  const size_t FB = (size_t)16384 * 512 * 2;   // 16 MiB bf16 buffer
  u16* fq  = (u16*)(ws);
  u16* kT  = (u16*)(ws + FB);
  u16* vT  = (u16*)(ws + 2*FB);
  u16* ao  = (u16*)(ws + 3*FB);
  u16* WpT   = (u16*)(ws + 4*FB);
  u16* WoutT = (u16*)(ws + 4*FB + 524288);
  float* g1  = (float*)(ws + 4*FB + 1048576);
  float* g2  = (float*)(ws + 4*FB + 1048576 + 2048);
  float* qstat = (float*)d_out;            // scratch in d_out (dead before out-GEMM)
  float* kstat = qstat + 262144;

  prep_k<<<528, 256, 0, stream>>>(Win, Wout, lnw, lnb, WpT, WoutT, g1, g2);

  // merged Q/K/V fused-LN projection: blocks [0,512) Q, [512,1024) K, [1024,1536) V
  proj_k<<<1536, 256, 0, stream>>>(q, k, v, WpT, g1, g2, fq, kT, vT, qstat, kstat);

  attn_k<<<256, 512, 0, stream>>>(fq, kT, vT, qstat, kstat, ao, cwr, vwr);

  outgemm_k<<<512, 256, 0, stream>>>(ao, WoutT, (float*)d_out, bout);
}

// Round 20
// 95.098 us; speedup vs baseline: 3.4215x; 3.4215x over previous
//
#include <hip/hip_runtime.h>
#include <stdint.h>

using u16 = unsigned short;
using u32 = unsigned int;
using bf16x8 = __bf16 __attribute__((ext_vector_type(8)));
using f32x4  = float __attribute__((ext_vector_type(4)));

__device__ __forceinline__ float bflo(u32 u){ return __uint_as_float(u << 16); }
__device__ __forceinline__ float bfhi(u32 u){ return __uint_as_float(u & 0xffff0000u); }
__device__ __forceinline__ u16 f2bf(float f){
  u32 u = __float_as_uint(f);
  u += 0x7fffu + ((u >> 16) & 1u);
  return (u16)(u >> 16);
}
// packed RTNE convert: lo = bf16(a), hi = bf16(b) — single instruction on gfx950
__device__ __forceinline__ u32 pk2(float a, float b){
  u32 r;
  asm("v_cvt_pk_bf16_f32 %0, %1, %2" : "=v"(r) : "v"(a), "v"(b));
  return r;
}
__device__ __forceinline__ void gload16(const void* g, void* l){
  __builtin_amdgcn_global_load_lds(
      (const __attribute__((address_space(1))) void*)(uintptr_t)(g),
      (__attribute__((address_space(3))) void*)(uintptr_t)(l), 16, 0, 0);
}

// ---------------- prep: WpT = (diag(lnw)Win)^T, WoutT, g1 = lnw^T Win, g2 = lnb^T Win ----
__global__ __launch_bounds__(256) void prep_k(const float* __restrict__ Win,
                                              const float* __restrict__ Wout,
                                              const float* __restrict__ lnw,
                                              const float* __restrict__ lnb,
                                              u16* __restrict__ WpT,
                                              u16* __restrict__ WoutT,
                                              float* __restrict__ g1,
                                              float* __restrict__ g2){
  __shared__ float tile[32][33];
  __shared__ float red[2][8][32];
  int bid = blockIdx.x;
  if (bid < 512){
    int bz = bid >> 8, bi = bid & 255;
    int bx = bi & 15, by = bi >> 4;
    const float* src = bz ? Wout : Win;
    u16* dst = bz ? WoutT : WpT;
    int tx = threadIdx.x & 31, ty = threadIdx.x >> 5;
    int c0 = bx * 32, r0 = by * 32;
#pragma unroll
    for (int i = 0; i < 4; ++i)
      tile[ty + i*8][tx] = src[(size_t)(r0 + ty + i*8)*512 + c0 + tx];
    __syncthreads();
    float sc = bz ? 1.f : lnw[r0 + tx];
#pragma unroll
    for (int i = 0; i < 4; ++i)
      dst[(size_t)(c0 + ty + i*8)*512 + r0 + tx] = f2bf(tile[tx][ty + i*8] * sc);
  } else {
    int bi = bid - 512;                       // 0..15
    int col = bi*32 + (threadIdx.x & 31);
    int s = threadIdx.x >> 5;                 // 0..7
    float p1 = 0.f, p2 = 0.f;
    for (int kk = 0; kk < 64; ++kk){
      int k = s*64 + kk;
      float wv = Win[(size_t)k*512 + col];
      p1 += lnw[k]*wv; p2 += lnb[k]*wv;
    }
    red[0][s][threadIdx.x & 31] = p1;
    red[1][s][threadIdx.x & 31] = p2;
    __syncthreads();
    if (threadIdx.x < 32){
      float a1 = 0.f, a2 = 0.f;
#pragma unroll
      for (int s2 = 0; s2 < 8; ++s2){ a1 += red[0][s2][threadIdx.x]; a2 += red[1][s2][threadIdx.x]; }
      g1[bi*32 + threadIdx.x] = a1;
      g2[bi*32 + threadIdx.x] = a2;
    }
  }
}

// ---------------- fused LN-GEMM projection body, 128x128 tile, BK=64 ----------------
// Pipelined: x(t+1) global->reg issued during MFMA(t); barrier2 drains lgkm ONLY
// (raw s_barrier, no vmcnt) so the prefetch stays in flight.
// GEMM on raw bf16(x); LN applied in epilogue: f = rs*(x@Wp - mu*g1) + g2.
// ORIENT 0: C[token][inner]   (A = x, B = WpT)
// ORIENT 1: C[inner][token]   (A = WpT, B = x)
// FSTAT: 0 none, 1 per-token-per-head (sum,ss) of f rows, 2 same for cols.
template<int ORIENT, int FSTAT>
__device__ __forceinline__ void proj_body(
    const float* __restrict__ X, const u16* __restrict__ Wp,
    const float* __restrict__ g1, const float* __restrict__ g2,
    u16* __restrict__ C, float* __restrict__ fstat, int ldC, int bid,
    char* sW, char* sX, float* sF){
  float* sMu = sF;        float* sRs = sF + 128;
  float* sG1 = sF + 256;  float* sG2 = sF + 384;
  const int t = threadIdx.x, w = t >> 6, l = t & 63;
  const int wr = w >> 1, wc = w & 1;
  const int lr = l & 15, lg = l >> 4;
  int bx, by;
  if (ORIENT == 0){ bx = bid & 127; by = bid >> 7; }          // siblings (+128) share XCD
  else { int j = bid >> 3; bx = j & 3; by = (bid & 7) + 8*(j >> 2); }  // token-panel siblings share XCD
  const int row0 = bx * 128, col0 = by * 128;
  const int xbase = (ORIENT == 0) ? row0 : col0;   // token rows of X
  const int wbase = (ORIENT == 0) ? col0 : row0;   // inner rows of Wp

  const int sc = t >> 3, k8 = t & 7;
  const int sso = (k8*16) ^ ((sc & 7) << 4);
  const char* Wpp = (const char*)Wp + ((size_t)(wbase + sc) << 10) + sso;
  const float* Xp = X + ((size_t)(xbase + sc) << 9) + k8*8;

  if (t < 128){ sG1[t] = g1[wbase + t]; sG2[t] = g2[wbase + t]; }

  float xr[4][8];
  float psum[4] = {}, pss[4] = {};
  f32x4 acc[4][4] = {};

  auto XLOAD = [&](int kt){
#pragma unroll
    for (int ii = 0; ii < 4; ++ii){
      const float* p = Xp + ii*(32*512) + kt*64;
      float4 a = *(const float4*)p, c4 = *(const float4*)(p + 4);
      xr[ii][0]=a.x;  xr[ii][1]=a.y;  xr[ii][2]=a.z;  xr[ii][3]=a.w;
      xr[ii][4]=c4.x; xr[ii][5]=c4.y; xr[ii][6]=c4.z; xr[ii][7]=c4.w;
    }
  };
  auto XWRITE = [&](){
#pragma unroll
    for (int ii = 0; ii < 4; ++ii){
#pragma unroll
      for (int e = 0; e < 8; ++e){ psum[ii] += xr[ii][e]; pss[ii] += xr[ii][e]*xr[ii][e]; }
      uint4 pk;
      pk.x = pk2(xr[ii][0], xr[ii][1]); pk.y = pk2(xr[ii][2], xr[ii][3]);
      pk.z = pk2(xr[ii][4], xr[ii][5]); pk.w = pk2(xr[ii][6], xr[ii][7]);
      *(uint4*)(sX + (sc + ii*32)*128 + sso) = pk;
    }
  };
  auto WSTAGE = [&](int kt){
#pragma unroll
    for (int ii = 0; ii < 4; ++ii)
      gload16(Wpp + (size_t)ii*32768 + kt*128, sW + ii*4096 + w*1024);
  };

  XLOAD(0);
  for (int kt = 0; kt < 8; ++kt){
    // Phase A: stage tile kt (W gloads issued first so latency hides under convert)
    WSTAGE(kt);
    XWRITE();
    // barrier1: full drain — gload_lds data must be LDS-visible to all waves
    asm volatile("s_waitcnt vmcnt(0) lgkmcnt(0)" ::: "memory");
    __builtin_amdgcn_s_barrier();
    __builtin_amdgcn_sched_barrier(0);
    // Phase B: issue x prefetch for kt+1, then compute
    if (kt < 7) XLOAD(kt + 1);
    __builtin_amdgcn_sched_barrier(0);
    const char* aB = (ORIENT == 0) ? sX : sW;
    const char* bB = (ORIENT == 0) ? sW : sX;
#pragma unroll
    for (int kk = 0; kk < 2; ++kk){
      bf16x8 af[4], bfg[4];
#pragma unroll
      for (int m = 0; m < 4; ++m){
        int r = wr*64 + m*16 + lr;
        af[m] = *(const bf16x8*)(aB + r*128 + ((kk*64 + lg*16) ^ ((r & 7) << 4)));
      }
#pragma unroll
      for (int n = 0; n < 4; ++n){
        int r = wc*64 + n*16 + lr;
        bfg[n] = *(const bf16x8*)(bB + r*128 + ((kk*64 + lg*16) ^ ((r & 7) << 4)));
      }
#pragma unroll
      for (int m = 0; m < 4; ++m)
#pragma unroll
        for (int n = 0; n < 4; ++n)
          acc[m][n] = __builtin_amdgcn_mfma_f32_16x16x32_bf16(af[m], bfg[n], acc[m][n], 0, 0, 0);
    }
    // barrier2: lgkm-only (raw barrier) — x prefetch stays in flight
    asm volatile("s_waitcnt lgkmcnt(0)" ::: "memory");
    __builtin_amdgcn_s_barrier();
    __builtin_amdgcn_sched_barrier(0);
  }

  // LN row stats: reduce over the 8 k8-lanes sharing each staged row
#pragma unroll
  for (int ii = 0; ii < 4; ++ii){
    float s = psum[ii], s2 = pss[ii];
#pragma unroll
    for (int off = 1; off < 8; off <<= 1){ s += __shfl_xor(s, off); s2 += __shfl_xor(s2, off); }
    if (k8 == 0){
      float mu = s * (1.f/512.f);
      sMu[sc + ii*32] = mu;
      sRs[sc + ii*32] = rsqrtf(s2 * (1.f/512.f) - mu*mu + 1e-5f);
    }
  }
  __syncthreads();

  // epilogue: f = rs*(acc - mu*g1) + g2, write bf16, emit f-stats
  float cs[4] = {}, cs2[4] = {};
#pragma unroll
  for (int m = 0; m < 4; ++m){
#pragma unroll
    for (int q = 0; q < 4; ++q){
      int ri = wr*64 + m*16 + lg*4 + q;
      float rsv = 0.f, muv = 0.f, g1r = 0.f, g2r = 0.f;
      if (ORIENT == 0){ rsv = sRs[ri]; muv = sMu[ri]; }
      else { g1r = sG1[ri]; g2r = sG2[ri]; }
      float fv[4];
#pragma unroll
      for (int n = 0; n < 4; ++n){
        int ci = wc*64 + n*16 + lr;
        float a = acc[m][n][q];
        if (ORIENT == 0) fv[n] = rsv*(a - muv*sG1[ci]) + sG2[ci];
        else             fv[n] = sRs[ci]*(a - sMu[ci]*g1r) + g2r;
        C[(size_t)(row0 + ri)*ldC + (col0 + ci)] = f2bf(fv[n]);
        if (FSTAT == 2){ cs[n] += fv[n]; cs2[n] += fv[n]*fv[n]; }
      }
      if (FSTAT == 1){
        float s  = (fv[0]+fv[1]) + (fv[2]+fv[3]);
        float s2 = (fv[0]*fv[0]+fv[1]*fv[1]) + (fv[2]*fv[2]+fv[3]*fv[3]);
#pragma unroll
        for (int off = 1; off < 16; off <<= 1){ s += __shfl_xor(s, off); s2 += __shfl_xor(s2, off); }
        if (lr == 0){
          int head = (col0 >> 6) + wc;
          *(float2*)(fstat + ((size_t)(row0 + ri)*8 + head)*2) = make_float2(s, s2);
        }
      }
    }
  }
  if (FSTAT == 2){
    int head = (row0 >> 6) + wr;
#pragma unroll
    for (int n = 0; n < 4; ++n){
      float s = cs[n], s2 = cs2[n];
      s += __shfl_xor(s, 16); s2 += __shfl_xor(s2, 16);
      s += __shfl_xor(s, 32); s2 += __shfl_xor(s2, 32);
      if (lg == 0){
        int tok = col0 + wc*64 + n*16 + lr;
        *(float2*)(fstat + ((size_t)tok*8 + head)*2) = make_float2(s, s2);
      }
    }
  }
}

// ---------------- merged Q/K/V projection launch: 1536 blocks ----------------
__global__ __launch_bounds__(256, 3) void proj_k(
    const float* __restrict__ q, const float* __restrict__ k, const float* __restrict__ v,
    const u16* __restrict__ Wp, const float* __restrict__ g1, const float* __restrict__ g2,
    u16* __restrict__ fq, u16* __restrict__ kT, u16* __restrict__ vT,
    float* __restrict__ qstat, float* __restrict__ kstat){
  __shared__ __align__(16) char sW[16384];
  __shared__ __align__(16) char sX[16384];
  __shared__ float sF[512];
  int bid = blockIdx.x;
  if (bid < 512)
    proj_body<0,1>(q, Wp, g1, g2, fq, qstat, 512, bid, sW, sX, sF);
  else if (bid < 1024)
    proj_body<1,2>(k, Wp, g1, g2, kT, kstat, 16384, bid - 512, sW, sX, sF);
  else
    proj_body<1,0>(v, Wp, g1, g2, vT, nullptr, 16384, bid - 1024, sW, sX, sF);
}

// ---------------- out GEMM (deep-pipelined): C = ao @ WoutT^T + bias ----------------
__global__ __launch_bounds__(256) void outgemm_k(
    const u16* __restrict__ A, const u16* __restrict__ B,
    float* __restrict__ Cf, const float* __restrict__ bias){
  __shared__ __align__(16) char sM[65536];
  const int t = threadIdx.x, w = t >> 6, l = t & 63;
  const int wr = w >> 1, wc = w & 1;
  const int lr = l & 15, lg = l >> 4;
  const int bx = blockIdx.x & 127, by = blockIdx.x >> 7;
  const int row0 = bx*128, col0 = by*128;

  const int spr = t >> 3, se = (t & 7) ^ (spr & 7);
  const int srow = spr*2 + (se >> 2), sk16 = se & 3;
  const char* Ap0 = (const char*)A + ((size_t)(row0 + srow) << 10) + sk16*16;
  const char* Bp0 = (const char*)B + ((size_t)(col0 + srow) << 10) + sk16*16;
  const int ldst = w*1024 + l*16;

  const int qf = ((((lr & 1) << 2) | lg) ^ ((lr >> 1) & 7)) * 16;
  const int afb = wr*4096 + (lr >> 1)*128 + qf;
  const int bfb = wc*4096 + (lr >> 1)*128 + qf;

  f32x4 acc[4][4] = {};

  auto STAGE = [&](int kt, int buf){
    char* d = sM + buf*16384;
    gload16(Ap0 + kt*64,         d + ldst);
    gload16(Ap0 + 65536 + kt*64, d + 4096 + ldst);
    gload16(Bp0 + kt*64,         d + 8192 + ldst);
    gload16(Bp0 + 65536 + kt*64, d + 12288 + ldst);
  };

  STAGE(0, 0); STAGE(1, 1); STAGE(2, 2);
#pragma unroll
  for (int kt = 0; kt < 16; ++kt){
    if (kt < 14)       asm volatile("s_waitcnt vmcnt(8)" ::: "memory");
    else if (kt == 14) asm volatile("s_waitcnt vmcnt(4)" ::: "memory");
    else               asm volatile("s_waitcnt vmcnt(0)" ::: "memory");
    __builtin_amdgcn_s_barrier();
    __builtin_amdgcn_sched_barrier(0);
    if (kt < 13) STAGE(kt + 3, (kt + 3) & 3);
    const char* aR = sM + (kt & 3)*16384;
    const char* bR = aR + 8192;
    bf16x8 af[4], bfg[4];
#pragma unroll
    for (int m = 0; m < 4; ++m) af[m]  = *(const bf16x8*)(aR + afb + m*1024);
#pragma unroll
    for (int n = 0; n < 4; ++n) bfg[n] = *(const bf16x8*)(bR + bfb + n*1024);
#pragma unroll
    for (int m = 0; m < 4; ++m)
#pragma unroll
      for (int n = 0; n < 4; ++n)
        acc[m][n] = __builtin_amdgcn_mfma_f32_16x16x32_bf16(af[m], bfg[n], acc[m][n], 0, 0, 0);
  }

#pragma unroll
  for (int m = 0; m < 4; ++m){
#pragma unroll
    for (int qq = 0; qq < 4; ++qq){
      int r = row0 + wr*64 + m*16 + lg*4 + qq;
#pragma unroll
      for (int n = 0; n < 4; ++n){
        int cc = col0 + wc*64 + n*16 + lr;
        Cf[(size_t)r*512 + cc] = acc[m][n][qq] + bias[cc];
      }
    }
  }
}

// ---------------- attention: per (h,b), factored rank-64 form, MFMA ----------------
__global__ __launch_bounds__(512) void attn_k(
    const u16* __restrict__ fq, const u16* __restrict__ kT, const u16* __restrict__ vT,
    const float* __restrict__ qstat, const float* __restrict__ kstat,
    u16* __restrict__ ao,
    const float* __restrict__ cwr, const float* __restrict__ vwr){
  __shared__ __align__(16) char smem[131072 + 1664*4];
  float* sStat = (float*)(smem + 131072);
  float* sS1 = sStat + 1536;
  float* sS2 = sStat + 1600;

  const int t = threadIdx.x, w = t >> 6, l = t & 63;
  const int lr = l & 15, lg = l >> 4;
  const int h = blockIdx.x & 7, b = blockIdx.x >> 3;

  float cwv = 1.f/(1.f + __expf(-*cwr));
  float vwv = 1.f/(1.f + __expf(-*vwr));
  float cosw = 1.f - cwv - vwv;

  const char* kTb = (const char*)kT + (size_t)h*64*32768 + (size_t)b*1024;
  const char* vTb = (const char*)vT + (size_t)h*64*32768 + (size_t)b*1024;
#pragma unroll
  for (int ii = 0; ii < 8; ++ii){
    int c = ii*512 + t, d = c >> 6, u = c & 63;
    int so = d*32768 + ((u ^ (d & 7)) << 4);
    gload16(kTb + so, smem + ii*8192 + w*1024);
    gload16(vTb + so, smem + 65536 + ii*8192 + w*1024);
  }
  {
    float2 ksr = *(const float2*)(kstat + ((size_t)(b*512 + t)*8 + h)*2);
    float mk = ksr.x * (1.f/64.f);
    sStat[t]        = rsqrtf(ksr.y);
    sStat[512 + t]  = mk;
    sStat[1024 + t] = (ksr.y - 64.f*mk*mk) * (1.f/63.f);
  }
  __syncthreads();

  const int jt = (w >> 1), itp = (w & 1);
  f32x4 m2acc[2] = {}, m1acc[2] = {};
  {
    const int j = jt*16 + lr;
#pragma unroll
    for (int ks = 0; ks < 16; ++ks){
      int u = ks*4 + lg;
      bf16x8 af = *(const bf16x8*)(smem + 65536 + j*1024 + ((u ^ (j & 7)) << 4));
#pragma unroll
      for (int tt = 0; tt < 2; ++tt){
        int i = (itp*2 + tt)*16 + lr;
        bf16x8 bf = *(const bf16x8*)(smem + i*1024 + ((u ^ (i & 7)) << 4));
        m2acc[tt] = __builtin_amdgcn_mfma_f32_16x16x32_bf16(af, bf, m2acc[tt], 0, 0, 0);
      }
    }
  }
  {
    int j = t >> 3, g = t & 7;
    float p1 = 0.f, p2 = 0.f;
#pragma unroll
    for (int uu = 0; uu < 8; ++uu){
      int ut = g*8 + uu;
      uint4 uv = *(const uint4*)(smem + 65536 + j*1024 + ((ut ^ (j & 7)) << 4));
      int m0 = ut*8;
      float4 mk0 = *(const float4*)(sStat + 512 + m0);
      float4 mk1 = *(const float4*)(sStat + 512 + m0 + 4);
      float4 kv0 = *(const float4*)(sStat + 1024 + m0);
      float4 kv1 = *(const float4*)(sStat + 1024 + m0 + 4);
      float v0=bflo(uv.x),v1=bfhi(uv.x),v2=bflo(uv.y),v3=bfhi(uv.y);
      float v4=bflo(uv.z),v5=bfhi(uv.z),v6=bflo(uv.w),v7=bfhi(uv.w);
      p1 += v0*mk0.x + v1*mk0.y + v2*mk0.z + v3*mk0.w
          + v4*mk1.x + v5*mk1.y + v6*mk1.z + v7*mk1.w;
      p2 += v0*kv0.x + v1*kv0.y + v2*kv0.z + v3*kv0.w
          + v4*kv1.x + v5*kv1.y + v6*kv1.z + v7*kv1.w;
    }
#pragma unroll
    for (int off = 1; off < 8; off <<= 1){ p1 += __shfl_xor(p1, off); p2 += __shfl_xor(p2, off); }
    if (g == 0){ sS1[j] = p1; sS2[j] = p2; }
  }
  __syncthreads();

#pragma unroll
  for (int ii = 0; ii < 32; ++ii){
    int wd = ii*512 + t;
    int d = wd >> 8, o = wd & 255, ud = o >> 2, p = o & 3;
    int m0 = ((ud ^ (d & 7)) << 3) + p*2;
    u32 uv = *(u32*)(smem + wd*4);
    *(u32*)(smem + wd*4) = pk2(bflo(uv)*sStat[m0], bfhi(uv)*sStat[m0+1]);
  }
  __syncthreads();

  {
    const int j = jt*16 + lr;
#pragma unroll
    for (int ks = 0; ks < 16; ++ks){
      int u = ks*4 + lg;
      bf16x8 af = *(const bf16x8*)(smem + 65536 + j*1024 + ((u ^ (j & 7)) << 4));
#pragma unroll
      for (int tt = 0; tt < 2; ++tt){
        int i = (itp*2 + tt)*16 + lr;
        bf16x8 bf = *(const bf16x8*)(smem + i*1024 + ((u ^ (i & 7)) << 4));
        m1acc[tt] = __builtin_amdgcn_mfma_f32_16x16x32_bf16(af, bf, m1acc[tt], 0, 0, 0);
      }
    }
  }
  __syncthreads();

#pragma unroll
  for (int tt = 0; tt < 2; ++tt){
#pragma unroll
    for (int q = 0; q < 4; ++q){
      int j = jt*16 + lg*4 + q;
      int i = (itp*2 + tt)*16 + lr;
      int bo = j*128 + (((i >> 3) ^ (j & 7)) << 4) + (i & 7)*2;
      *(u16*)(smem + bo)        = f2bf(m1acc[tt][q]);
      *(u16*)(smem + 8192 + bo) = f2bf(m2acc[tt][q]);
    }
  }
  const char* fqb = (const char*)fq + (size_t)b*524288 + h*128;
#pragma unroll
  for (int ii = 0; ii < 8; ++ii){
    int c = ii*512 + t, n = c >> 3, u = c & 7;
    gload16(fqb + n*1024 + ((u ^ (n & 7)) << 4), smem + 65536 + ii*8192 + w*1024);
  }
  __syncthreads();

  float s1v[4], s2v[4];
#pragma unroll
  for (int nt = 0; nt < 4; ++nt){ s1v[nt] = sS1[nt*16 + lr]; s2v[nt] = sS2[nt*16 + lr]; }
  const float Bc = cwv * (1.f/64.f);

#pragma unroll
  for (int mt = 0; mt < 4; ++mt){
    f32x4 a1[4] = {}, a2[4] = {};
    const int n = w*64 + mt*16 + lr;
#pragma unroll
    for (int kk = 0; kk < 2; ++kk){
      int u = kk*4 + lg;
      bf16x8 af = *(const bf16x8*)(smem + 65536 + n*128 + ((u ^ (n & 7)) << 4));
#pragma unroll
      for (int nt = 0; nt < 4; ++nt){
        int j = nt*16 + lr;
        bf16x8 b1 = *(const bf16x8*)(smem + j*128 + ((u ^ (j & 7)) << 4));
        bf16x8 b2 = *(const bf16x8*)(smem + 8192 + j*128 + ((u ^ (j & 7)) << 4));
        a1[nt] = __builtin_amdgcn_mfma_f32_16x16x32_bf16(af, b1, a1[nt], 0, 0, 0);
        a2[nt] = __builtin_amdgcn_mfma_f32_16x16x32_bf16(af, b2, a2[nt], 0, 0, 0);
      }
    }
#pragma unroll
    for (int q = 0; q < 4; ++q){
      int nr = w*64 + mt*16 + lg*4 + q;
      float2 qs = *(const float2*)(qstat + ((size_t)(b*512 + nr)*8 + h)*2);
      float mq = qs.x * (1.f/64.f);
      float An = cosw * rsqrtf(qs.y);
      float Cn = -cwv * mq;
      float En = vwv * (1.f/64.f) * ((qs.y - 64.f*mq*mq) * (1.f/63.f));
      char* op = (char*)ao + ((size_t)(b*512 + nr)*512 + h*64)*2;
#pragma unroll
      for (int nt = 0; nt < 4; ++nt){
        float ov = An*a1[nt][q] + Bc*a2[nt][q] + Cn*s1v[nt] + En*s2v[nt];
        *(u16*)(op + (nt*16 + lr)*2) = f2bf(ov);
      }
    }
  }
}

// ---------------- launch ----------------
extern "C" void kernel_launch(void* const* d_in, const int* in_sizes, int n_in,
                              void* d_out, int out_size, void* d_ws, size_t ws_size,
                              hipStream_t stream){
  const float* q    = (const float*)d_in[0];
  const float* k    = (const float*)d_in[1];
  const float* v    = (const float*)d_in[2];
  const float* lnw  = (const float*)d_in[3];
  const float* lnb  = (const float*)d_in[4];
  const float* Win  = (const float*)d_in[5];
  const float* Wout = (const float*)d_in[6];
  const float* bout = (const float*)d_in[7];
  const float* cwr  = (const float*)d_in[8];
  const float* vwr  = (const float*)d_in[9];

  char* ws = (char*)d_ws;
  const size_t FB = (size_t)16384 * 512 * 2;   // 16 MiB bf16 buffer
  u16* fq  = (u16*)(ws);
  u16* kT  = (u16*)(ws + FB);
  u16* vT  = (u16*)(ws + 2*FB);
  u16* ao  = (u16*)(ws + 3*FB);
  u16* WpT   = (u16*)(ws + 4*FB);
  u16* WoutT = (u16*)(ws + 4*FB + 524288);
  float* g1  = (float*)(ws + 4*FB + 1048576);
  float* g2  = (float*)(ws + 4*FB + 1048576 + 2048);
  float* qstat = (float*)d_out;            // scratch in d_out (dead before out-GEMM)
  float* kstat = qstat + 262144;

  prep_k<<<528, 256, 0, stream>>>(Win, Wout, lnw, lnb, WpT, WoutT, g1, g2);

  // merged Q/K/V fused-LN projection: blocks [0,512) Q, [512,1024) K, [1024,1536) V
  proj_k<<<1536, 256, 0, stream>>>(q, k, v, WpT, g1, g2, fq, kT, vT, qstat, kstat);

  attn_k<<<256, 512, 0, stream>>>(fq, kT, vT, qstat, kstat, ao, cwr, vwr);

  outgemm_k<<<512, 256, 0, stream>>>(ao, WoutT, (float*)d_out, bout);
}

// Round 21
// 94.574 us; speedup vs baseline: 3.4405x; 1.0055x over previous
//
#include <hip/hip_runtime.h>
#include <stdint.h>

using u16 = unsigned short;
using u32 = unsigned int;
using bf16x8 = __bf16 __attribute__((ext_vector_type(8)));
using f32x4  = float __attribute__((ext_vector_type(4)));

__device__ __forceinline__ float bflo(u32 u){ return __uint_as_float(u << 16); }
__device__ __forceinline__ float bfhi(u32 u){ return __uint_as_float(u & 0xffff0000u); }
__device__ __forceinline__ u16 f2bf(float f){
  u32 u = __float_as_uint(f);
  u += 0x7fffu + ((u >> 16) & 1u);
  return (u16)(u >> 16);
}
// packed RTNE convert: lo = bf16(a), hi = bf16(b) — single instruction on gfx950
__device__ __forceinline__ u32 pk2(float a, float b){
  u32 r;
  asm("v_cvt_pk_bf16_f32 %0, %1, %2" : "=v"(r) : "v"(a), "v"(b));
  return r;
}
__device__ __forceinline__ void gload16(const void* g, void* l){
  __builtin_amdgcn_global_load_lds(
      (const __attribute__((address_space(1))) void*)(uintptr_t)(g),
      (__attribute__((address_space(3))) void*)(uintptr_t)(l), 16, 0, 0);
}

// ---------------- prep: WpT = (diag(lnw)Win)^T, WoutT, g1 = lnw^T Win, g2 = lnb^T Win ----
__global__ __launch_bounds__(256) void prep_k(const float* __restrict__ Win,
                                              const float* __restrict__ Wout,
                                              const float* __restrict__ lnw,
                                              const float* __restrict__ lnb,
                                              u16* __restrict__ WpT,
                                              u16* __restrict__ WoutT,
                                              float* __restrict__ g1,
                                              float* __restrict__ g2){
  __shared__ float tile[32][33];
  __shared__ float red[2][8][32];
  int bid = blockIdx.x;
  if (bid < 512){
    int bz = bid >> 8, bi = bid & 255;
    int bx = bi & 15, by = bi >> 4;
    const float* src = bz ? Wout : Win;
    u16* dst = bz ? WoutT : WpT;
    int tx = threadIdx.x & 31, ty = threadIdx.x >> 5;
    int c0 = bx * 32, r0 = by * 32;
#pragma unroll
    for (int i = 0; i < 4; ++i)
      tile[ty + i*8][tx] = src[(size_t)(r0 + ty + i*8)*512 + c0 + tx];
    __syncthreads();
    float sc = bz ? 1.f : lnw[r0 + tx];
#pragma unroll
    for (int i = 0; i < 4; ++i)
      dst[(size_t)(c0 + ty + i*8)*512 + r0 + tx] = f2bf(tile[tx][ty + i*8] * sc);
  } else {
    int bi = bid - 512;                       // 0..15
    int col = bi*32 + (threadIdx.x & 31);
    int s = threadIdx.x >> 5;                 // 0..7
    float p1 = 0.f, p2 = 0.f;
    for (int kk = 0; kk < 64; ++kk){
      int k = s*64 + kk;
      float wv = Win[(size_t)k*512 + col];
      p1 += lnw[k]*wv; p2 += lnb[k]*wv;
    }
    red[0][s][threadIdx.x & 31] = p1;
    red[1][s][threadIdx.x & 31] = p2;
    __syncthreads();
    if (threadIdx.x < 32){
      float a1 = 0.f, a2 = 0.f;
#pragma unroll
      for (int s2 = 0; s2 < 8; ++s2){ a1 += red[0][s2][threadIdx.x]; a2 += red[1][s2][threadIdx.x]; }
      g1[bi*32 + threadIdx.x] = a1;
      g2[bi*32 + threadIdx.x] = a2;
    }
  }
}

// ---------------- fused LN-GEMM projection body, 128x128 tile, BK=64 ----------------
// r13 structure + 1-iteration W prefetch via DOUBLE-BUFFERED sW (register-free):
//   prologue: WSTAGE(0->b0); XLOAD(0)    (W oldest -> XWRITE's x-wait drains it)
//   A(kt): XWRITE(kt) [drains x(kt) and older W(kt)]; WSTAGE(kt+1 -> b_{kt+1})
//   barrier1: vmcnt(4) lgkmcnt(0)  -- W(kt+1)'s 4 DMAs stay in flight
//   B(kt): XLOAD(kt+1); MFMA reads buf kt&1  (buf kt+1 sealed by barrier2(kt-1))
//   barrier2: lgkmcnt(0)-only raw barrier -- all global prefetches stay in flight
// GEMM on raw bf16(x); LN applied in epilogue: f = rs*(x@Wp - mu*g1) + g2.
template<int ORIENT, int FSTAT>
__device__ __forceinline__ void proj_body(
    const float* __restrict__ X, const u16* __restrict__ Wp,
    const float* __restrict__ g1, const float* __restrict__ g2,
    u16* __restrict__ C, float* __restrict__ fstat, int ldC, int bid,
    char* sW, char* sX, float* sF){
  float* sMu = sF;        float* sRs = sF + 128;
  float* sG1 = sF + 256;  float* sG2 = sF + 384;
  const int t = threadIdx.x, w = t >> 6, l = t & 63;
  const int wr = w >> 1, wc = w & 1;
  const int lr = l & 15, lg = l >> 4;
  int bx, by;
  if (ORIENT == 0){ bx = bid & 127; by = bid >> 7; }          // +128 siblings share XCD
  else { int j = bid >> 3; bx = j & 3; by = (bid & 7) + 8*(j >> 2); }
  const int row0 = bx * 128, col0 = by * 128;
  const int xbase = (ORIENT == 0) ? row0 : col0;   // token rows of X
  const int wbase = (ORIENT == 0) ? col0 : row0;   // inner rows of Wp

  const int sc = t >> 3, k8 = t & 7;
  const int sso = (k8*16) ^ ((sc & 7) << 4);
  const char* Wpp = (const char*)Wp + ((size_t)(wbase + sc) << 10) + sso;
  const float* Xp = X + ((size_t)(xbase + sc) << 9) + k8*8;

  if (t < 128){ sG1[t] = g1[wbase + t]; sG2[t] = g2[wbase + t]; }

  float xr[4][8];
  float psum[4] = {}, pss[4] = {};
  f32x4 acc[4][4] = {};

  auto XLOAD = [&](int kt){
#pragma unroll
    for (int ii = 0; ii < 4; ++ii){
      const float* p = Xp + ii*(32*512) + kt*64;
      float4 a = *(const float4*)p, c4 = *(const float4*)(p + 4);
      xr[ii][0]=a.x;  xr[ii][1]=a.y;  xr[ii][2]=a.z;  xr[ii][3]=a.w;
      xr[ii][4]=c4.x; xr[ii][5]=c4.y; xr[ii][6]=c4.z; xr[ii][7]=c4.w;
    }
  };
  auto XWRITE = [&](){
#pragma unroll
    for (int ii = 0; ii < 4; ++ii){
#pragma unroll
      for (int e = 0; e < 8; ++e){ psum[ii] += xr[ii][e]; pss[ii] += xr[ii][e]*xr[ii][e]; }
      uint4 pk;
      pk.x = pk2(xr[ii][0], xr[ii][1]); pk.y = pk2(xr[ii][2], xr[ii][3]);
      pk.z = pk2(xr[ii][4], xr[ii][5]); pk.w = pk2(xr[ii][6], xr[ii][7]);
      *(uint4*)(sX + (sc + ii*32)*128 + sso) = pk;
    }
  };
  auto WSTAGE = [&](int kt, int buf){
#pragma unroll
    for (int ii = 0; ii < 4; ++ii)
      gload16(Wpp + (size_t)ii*32768 + kt*128, sW + buf*16384 + ii*4096 + w*1024);
  };

  WSTAGE(0, 0);         // W(0) first (oldest) -> drained by XWRITE(0)'s x-wait
  XLOAD(0);
  for (int kt = 0; kt < 8; ++kt){
    // Phase A: pack x(kt); issue NEXT W into the other buffer
    XWRITE();
    if (kt < 7) WSTAGE(kt + 1, (kt + 1) & 1);
    // barrier1: W(kt) drained (older than x(kt)); W(kt+1)'s 4 DMAs stay in flight
    asm volatile("s_waitcnt vmcnt(4) lgkmcnt(0)" ::: "memory");
    __builtin_amdgcn_s_barrier();
    __builtin_amdgcn_sched_barrier(0);
    // Phase B: issue x prefetch for kt+1, then compute on buf kt&1
    if (kt < 7) XLOAD(kt + 1);
    __builtin_amdgcn_sched_barrier(0);
    const char* wB = sW + (kt & 1)*16384;
    const char* aB = (ORIENT == 0) ? sX : wB;
    const char* bB = (ORIENT == 0) ? wB : sX;
#pragma unroll
    for (int kk = 0; kk < 2; ++kk){
      bf16x8 af[4], bfg[4];
#pragma unroll
      for (int m = 0; m < 4; ++m){
        int r = wr*64 + m*16 + lr;
        af[m] = *(const bf16x8*)(aB + r*128 + ((kk*64 + lg*16) ^ ((r & 7) << 4)));
      }
#pragma unroll
      for (int n = 0; n < 4; ++n){
        int r = wc*64 + n*16 + lr;
        bfg[n] = *(const bf16x8*)(bB + r*128 + ((kk*64 + lg*16) ^ ((r & 7) << 4)));
      }
#pragma unroll
      for (int m = 0; m < 4; ++m)
#pragma unroll
        for (int n = 0; n < 4; ++n)
          acc[m][n] = __builtin_amdgcn_mfma_f32_16x16x32_bf16(af[m], bfg[n], acc[m][n], 0, 0, 0);
    }
    // barrier2: lgkm-only (raw barrier) — W/x prefetches stay in flight;
    // seals all waves' ds_reads of buf kt&1 and sX before overwrite.
    asm volatile("s_waitcnt lgkmcnt(0)" ::: "memory");
    __builtin_amdgcn_s_barrier();
    __builtin_amdgcn_sched_barrier(0);
  }

  // LN row stats: reduce over the 8 k8-lanes sharing each staged row
#pragma unroll
  for (int ii = 0; ii < 4; ++ii){
    float s = psum[ii], s2 = pss[ii];
#pragma unroll
    for (int off = 1; off < 8; off <<= 1){ s += __shfl_xor(s, off); s2 += __shfl_xor(s2, off); }
    if (k8 == 0){
      float mu = s * (1.f/512.f);
      sMu[sc + ii*32] = mu;
      sRs[sc + ii*32] = rsqrtf(s2 * (1.f/512.f) - mu*mu + 1e-5f);
    }
  }
  __syncthreads();

  // epilogue: f = rs*(acc - mu*g1) + g2, write bf16, emit f-stats
  float cs[4] = {}, cs2[4] = {};
#pragma unroll
  for (int m = 0; m < 4; ++m){
#pragma unroll
    for (int q = 0; q < 4; ++q){
      int ri = wr*64 + m*16 + lg*4 + q;
      float rsv = 0.f, muv = 0.f, g1r = 0.f, g2r = 0.f;
      if (ORIENT == 0){ rsv = sRs[ri]; muv = sMu[ri]; }
      else { g1r = sG1[ri]; g2r = sG2[ri]; }
      float fv[4];
#pragma unroll
      for (int n = 0; n < 4; ++n){
        int ci = wc*64 + n*16 + lr;
        float a = acc[m][n][q];
        if (ORIENT == 0) fv[n] = rsv*(a - muv*sG1[ci]) + sG2[ci];
        else             fv[n] = sRs[ci]*(a - sMu[ci]*g1r) + g2r;
        C[(size_t)(row0 + ri)*ldC + (col0 + ci)] = f2bf(fv[n]);
        if (FSTAT == 2){ cs[n] += fv[n]; cs2[n] += fv[n]*fv[n]; }
      }
      if (FSTAT == 1){
        float s  = (fv[0]+fv[1]) + (fv[2]+fv[3]);
        float s2 = (fv[0]*fv[0]+fv[1]*fv[1]) + (fv[2]*fv[2]+fv[3]*fv[3]);
#pragma unroll
        for (int off = 1; off < 16; off <<= 1){ s += __shfl_xor(s, off); s2 += __shfl_xor(s2, off); }
        if (lr == 0){
          int head = (col0 >> 6) + wc;
          *(float2*)(fstat + ((size_t)(row0 + ri)*8 + head)*2) = make_float2(s, s2);
        }
      }
    }
  }
  if (FSTAT == 2){
    int head = (row0 >> 6) + wr;
#pragma unroll
    for (int n = 0; n < 4; ++n){
      float s = cs[n], s2 = cs2[n];
      s += __shfl_xor(s, 16); s2 += __shfl_xor(s2, 16);
      s += __shfl_xor(s, 32); s2 += __shfl_xor(s2, 32);
      if (lg == 0){
        int tok = col0 + wc*64 + n*16 + lr;
        *(float2*)(fstat + ((size_t)tok*8 + head)*2) = make_float2(s, s2);
      }
    }
  }
}

// ---------------- merged Q/K/V projection launch: 1536 blocks ----------------
__global__ __launch_bounds__(256, 3) void proj_k(
    const float* __restrict__ q, const float* __restrict__ k, const float* __restrict__ v,
    const u16* __restrict__ Wp, const float* __restrict__ g1, const float* __restrict__ g2,
    u16* __restrict__ fq, u16* __restrict__ kT, u16* __restrict__ vT,
    float* __restrict__ qstat, float* __restrict__ kstat){
  __shared__ __align__(16) char sW[32768];     // double-buffered W
  __shared__ __align__(16) char sX[16384];
  __shared__ float sF[512];
  int bid = blockIdx.x;
  if (bid < 512)
    proj_body<0,1>(q, Wp, g1, g2, fq, qstat, 512, bid, sW, sX, sF);
  else if (bid < 1024)
    proj_body<1,2>(k, Wp, g1, g2, kT, kstat, 16384, bid - 512, sW, sX, sF);
  else
    proj_body<1,0>(v, Wp, g1, g2, vT, nullptr, 16384, bid - 1024, sW, sX, sF);
}

// ---------------- out GEMM (deep-pipelined): C = ao @ WoutT^T + bias ----------------
__global__ __launch_bounds__(256) void outgemm_k(
    const u16* __restrict__ A, const u16* __restrict__ B,
    float* __restrict__ Cf, const float* __restrict__ bias){
  __shared__ __align__(16) char sM[65536];
  const int t = threadIdx.x, w = t >> 6, l = t & 63;
  const int wr = w >> 1, wc = w & 1;
  const int lr = l & 15, lg = l >> 4;
  const int bx = blockIdx.x & 127, by = blockIdx.x >> 7;
  const int row0 = bx*128, col0 = by*128;

  const int spr = t >> 3, se = (t & 7) ^ (spr & 7);
  const int srow = spr*2 + (se >> 2), sk16 = se & 3;
  const char* Ap0 = (const char*)A + ((size_t)(row0 + srow) << 10) + sk16*16;
  const char* Bp0 = (const char*)B + ((size_t)(col0 + srow) << 10) + sk16*16;
  const int ldst = w*1024 + l*16;

  const int qf = ((((lr & 1) << 2) | lg) ^ ((lr >> 1) & 7)) * 16;
  const int afb = wr*4096 + (lr >> 1)*128 + qf;
  const int bfb = wc*4096 + (lr >> 1)*128 + qf;

  f32x4 acc[4][4] = {};

  auto STAGE = [&](int kt, int buf){
    char* d = sM + buf*16384;
    gload16(Ap0 + kt*64,         d + ldst);
    gload16(Ap0 + 65536 + kt*64, d + 4096 + ldst);
    gload16(Bp0 + kt*64,         d + 8192 + ldst);
    gload16(Bp0 + 65536 + kt*64, d + 12288 + ldst);
  };

  STAGE(0, 0); STAGE(1, 1); STAGE(2, 2);
#pragma unroll
  for (int kt = 0; kt < 16; ++kt){
    if (kt < 14)       asm volatile("s_waitcnt vmcnt(8)" ::: "memory");
    else if (kt == 14) asm volatile("s_waitcnt vmcnt(4)" ::: "memory");
    else               asm volatile("s_waitcnt vmcnt(0)" ::: "memory");
    __builtin_amdgcn_s_barrier();
    __builtin_amdgcn_sched_barrier(0);
    if (kt < 13) STAGE(kt + 3, (kt + 3) & 3);
    const char* aR = sM + (kt & 3)*16384;
    const char* bR = aR + 8192;
    bf16x8 af[4], bfg[4];
#pragma unroll
    for (int m = 0; m < 4; ++m) af[m]  = *(const bf16x8*)(aR + afb + m*1024);
#pragma unroll
    for (int n = 0; n < 4; ++n) bfg[n] = *(const bf16x8*)(bR + bfb + n*1024);
#pragma unroll
    for (int m = 0; m < 4; ++m)
#pragma unroll
      for (int n = 0; n < 4; ++n)
        acc[m][n] = __builtin_amdgcn_mfma_f32_16x16x32_bf16(af[m], bfg[n], acc[m][n], 0, 0, 0);
  }

#pragma unroll
  for (int m = 0; m < 4; ++m){
#pragma unroll
    for (int qq = 0; qq < 4; ++qq){
      int r = row0 + wr*64 + m*16 + lg*4 + qq;
#pragma unroll
      for (int n = 0; n < 4; ++n){
        int cc = col0 + wc*64 + n*16 + lr;
        Cf[(size_t)r*512 + cc] = acc[m][n][qq] + bias[cc];
      }
    }
  }
}

// ---------------- attention: per (h,b), factored rank-64 form, MFMA ----------------
__global__ __launch_bounds__(512) void attn_k(
    const u16* __restrict__ fq, const u16* __restrict__ kT, const u16* __restrict__ vT,
    const float* __restrict__ qstat, const float* __restrict__ kstat,
    u16* __restrict__ ao,
    const float* __restrict__ cwr, const float* __restrict__ vwr){
  __shared__ __align__(16) char smem[131072 + 1664*4];
  float* sStat = (float*)(smem + 131072);
  float* sS1 = sStat + 1536;
  float* sS2 = sStat + 1600;

  const int t = threadIdx.x, w = t >> 6, l = t & 63;
  const int lr = l & 15, lg = l >> 4;
  const int h = blockIdx.x & 7, b = blockIdx.x >> 3;

  float cwv = 1.f/(1.f + __expf(-*cwr));
  float vwv = 1.f/(1.f + __expf(-*vwr));
  float cosw = 1.f - cwv - vwv;

  const char* kTb = (const char*)kT + (size_t)h*64*32768 + (size_t)b*1024;
  const char* vTb = (const char*)vT + (size_t)h*64*32768 + (size_t)b*1024;
#pragma unroll
  for (int ii = 0; ii < 8; ++ii){
    int c = ii*512 + t, d = c >> 6, u = c & 63;
    int so = d*32768 + ((u ^ (d & 7)) << 4);
    gload16(kTb + so, smem + ii*8192 + w*1024);
    gload16(vTb + so, smem + 65536 + ii*8192 + w*1024);
  }
  {
    float2 ksr = *(const float2*)(kstat + ((size_t)(b*512 + t)*8 + h)*2);
    float mk = ksr.x * (1.f/64.f);
    sStat[t]        = rsqrtf(ksr.y);
    sStat[512 + t]  = mk;
    sStat[1024 + t] = (ksr.y - 64.f*mk*mk) * (1.f/63.f);
  }
  __syncthreads();

  const int jt = (w >> 1), itp = (w & 1);
  f32x4 m2acc[2] = {}, m1acc[2] = {};
  {
    const int j = jt*16 + lr;
#pragma unroll
    for (int ks = 0; ks < 16; ++ks){
      int u = ks*4 + lg;
      bf16x8 af = *(const bf16x8*)(smem + 65536 + j*1024 + ((u ^ (j & 7)) << 4));
#pragma unroll
      for (int tt = 0; tt < 2; ++tt){
        int i = (itp*2 + tt)*16 + lr;
        bf16x8 bf = *(const bf16x8*)(smem + i*1024 + ((u ^ (i & 7)) << 4));
        m2acc[tt] = __builtin_amdgcn_mfma_f32_16x16x32_bf16(af, bf, m2acc[tt], 0, 0, 0);
      }
    }
  }
  {
    int j = t >> 3, g = t & 7;
    float p1 = 0.f, p2 = 0.f;
#pragma unroll
    for (int uu = 0; uu < 8; ++uu){
      int ut = g*8 + uu;
      uint4 uv = *(const uint4*)(smem + 65536 + j*1024 + ((ut ^ (j & 7)) << 4));
      int m0 = ut*8;
      float4 mk0 = *(const float4*)(sStat + 512 + m0);
      float4 mk1 = *(const float4*)(sStat + 512 + m0 + 4);
      float4 kv0 = *(const float4*)(sStat + 1024 + m0);
      float4 kv1 = *(const float4*)(sStat + 1024 + m0 + 4);
      float v0=bflo(uv.x),v1=bfhi(uv.x),v2=bflo(uv.y),v3=bfhi(uv.y);
      float v4=bflo(uv.z),v5=bfhi(uv.z),v6=bflo(uv.w),v7=bfhi(uv.w);
      p1 += v0*mk0.x + v1*mk0.y + v2*mk0.z + v3*mk0.w
          + v4*mk1.x + v5*mk1.y + v6*mk1.z + v7*mk1.w;
      p2 += v0*kv0.x + v1*kv0.y + v2*kv0.z + v3*kv0.w
          + v4*kv1.x + v5*kv1.y + v6*kv1.z + v7*kv1.w;
    }
#pragma unroll
    for (int off = 1; off < 8; off <<= 1){ p1 += __shfl_xor(p1, off); p2 += __shfl_xor(p2, off); }
    if (g == 0){ sS1[j] = p1; sS2[j] = p2; }
  }
  __syncthreads();

#pragma unroll
  for (int ii = 0; ii < 32; ++ii){
    int wd = ii*512 + t;
    int d = wd >> 8, o = wd & 255, ud = o >> 2, p = o & 3;
    int m0 = ((ud ^ (d & 7)) << 3) + p*2;
    u32 uv = *(u32*)(smem + wd*4);
    *(u32*)(smem + wd*4) = pk2(bflo(uv)*sStat[m0], bfhi(uv)*sStat[m0+1]);
  }
  __syncthreads();

  {
    const int j = jt*16 + lr;
#pragma unroll
    for (int ks = 0; ks < 16; ++ks){
      int u = ks*4 + lg;
      bf16x8 af = *(const bf16x8*)(smem + 65536 + j*1024 + ((u ^ (j & 7)) << 4));
#pragma unroll
      for (int tt = 0; tt < 2; ++tt){
        int i = (itp*2 + tt)*16 + lr;
        bf16x8 bf = *(const bf16x8*)(smem + i*1024 + ((u ^ (i & 7)) << 4));
        m1acc[tt] = __builtin_amdgcn_mfma_f32_16x16x32_bf16(af, bf, m1acc[tt], 0, 0, 0);
      }
    }
  }
  __syncthreads();

#pragma unroll
  for (int tt = 0; tt < 2; ++tt){
#pragma unroll
    for (int q = 0; q < 4; ++q){
      int j = jt*16 + lg*4 + q;
      int i = (itp*2 + tt)*16 + lr;
      int bo = j*128 + (((i >> 3) ^ (j & 7)) << 4) + (i & 7)*2;
      *(u16*)(smem + bo)        = f2bf(m1acc[tt][q]);
      *(u16*)(smem + 8192 + bo) = f2bf(m2acc[tt][q]);
    }
  }
  const char* fqb = (const char*)fq + (size_t)b*524288 + h*128;
#pragma unroll
  for (int ii = 0; ii < 8; ++ii){
    int c = ii*512 + t, n = c >> 3, u = c & 7;
    gload16(fqb + n*1024 + ((u ^ (n & 7)) << 4), smem + 65536 + ii*8192 + w*1024);
  }
  __syncthreads();

  float s1v[4], s2v[4];
#pragma unroll
  for (int nt = 0; nt < 4; ++nt){ s1v[nt] = sS1[nt*16 + lr]; s2v[nt] = sS2[nt*16 + lr]; }
  const float Bc = cwv * (1.f/64.f);

#pragma unroll
  for (int mt = 0; mt < 4; ++mt){
    f32x4 a1[4] = {}, a2[4] = {};
    const int n = w*64 + mt*16 + lr;
#pragma unroll
    for (int kk = 0; kk < 2; ++kk){
      int u = kk*4 + lg;
      bf16x8 af = *(const bf16x8*)(smem + 65536 + n*128 + ((u ^ (n & 7)) << 4));
#pragma unroll
      for (int nt = 0; nt < 4; ++nt){
        int j = nt*16 + lr;
        bf16x8 b1 = *(const bf16x8*)(smem + j*128 + ((u ^ (j & 7)) << 4));
        bf16x8 b2 = *(const bf16x8*)(smem + 8192 + j*128 + ((u ^ (j & 7)) << 4));
        a1[nt] = __builtin_amdgcn_mfma_f32_16x16x32_bf16(af, b1, a1[nt], 0, 0, 0);
        a2[nt] = __builtin_amdgcn_mfma_f32_16x16x32_bf16(af, b2, a2[nt], 0, 0, 0);
      }
    }
#pragma unroll
    for (int q = 0; q < 4; ++q){
      int nr = w*64 + mt*16 + lg*4 + q;
      float2 qs = *(const float2*)(qstat + ((size_t)(b*512 + nr)*8 + h)*2);
      float mq = qs.x * (1.f/64.f);
      float An = cosw * rsqrtf(qs.y);
      float Cn = -cwv * mq;
      float En = vwv * (1.f/64.f) * ((qs.y - 64.f*mq*mq) * (1.f/63.f));
      char* op = (char*)ao + ((size_t)(b*512 + nr)*512 + h*64)*2;
#pragma unroll
      for (int nt = 0; nt < 4; ++nt){
        float ov = An*a1[nt][q] + Bc*a2[nt][q] + Cn*s1v[nt] + En*s2v[nt];
        *(u16*)(op + (nt*16 + lr)*2) = f2bf(ov);
      }
    }
  }
}

// ---------------- launch ----------------
extern "C" void kernel_launch(void* const* d_in, const int* in_sizes, int n_in,
                              void* d_out, int out_size, void* d_ws, size_t ws_size,
                              hipStream_t stream){
  const float* q    = (const float*)d_in[0];
  const float* k    = (const float*)d_in[1];
  const float* v    = (const float*)d_in[2];
  const float* lnw  = (const float*)d_in[3];
  const float* lnb  = (const float*)d_in[4];
  const float* Win  = (const float*)d_in[5];
  const float* Wout = (const float*)d_in[6];
  const float* bout = (const float*)d_in[7];
  const float* cwr  = (const float*)d_in[8];
  const float* vwr  = (const float*)d_in[9];

  char* ws = (char*)d_ws;
  const size_t FB = (size_t)16384 * 512 * 2;   // 16 MiB bf16 buffer
  u16* fq  = (u16*)(ws);
  u16* kT  = (u16*)(ws + FB);
  u16* vT  = (u16*)(ws + 2*FB);
  u16* ao  = (u16*)(ws + 3*FB);
  u16* WpT   = (u16*)(ws + 4*FB);
  u16* WoutT = (u16*)(ws + 4*FB + 524288);
  float* g1  = (float*)(ws + 4*FB + 1048576);
  float* g2  = (float*)(ws + 4*FB + 1048576 + 2048);
  float* qstat = (float*)d_out;            // scratch in d_out (dead before out-GEMM)
  float* kstat = qstat + 262144;

  prep_k<<<528, 256, 0, stream>>>(Win, Wout, lnw, lnb, WpT, WoutT, g1, g2);

  // merged Q/K/V fused-LN projection: blocks [0,512) Q, [512,1024) K, [1024,1536) V
  proj_k<<<1536, 256, 0, stream>>>(q, k, v, WpT, g1, g2, fq, kT, vT, qstat, kstat);

  attn_k<<<256, 512, 0, stream>>>(fq, kT, vT, qstat, kstat, ao, cwr, vwr);

  outgemm_k<<<512, 256, 0, stream>>>(ao, WoutT, (float*)d_out, bout);
}